// Round 3
// baseline (222.058 us; speedup 1.0000x reference)
//
#include <hip/hip_runtime.h>
#include <hip/hip_bf16.h>
#include <stdint.h>
#include <stddef.h>

typedef __bf16 bf16;
typedef __bf16 bf16x4 __attribute__((ext_vector_type(4)));
typedef __bf16 bf16x8 __attribute__((ext_vector_type(8)));
typedef float  f32x4  __attribute__((ext_vector_type(4)));
typedef float  f32x16 __attribute__((ext_vector_type(16)));

#define LOG2E 1.44269504f
#define QSCALE 0.18033688f   /* 0.125 * log2(e) */

// ---------------------------------------------------------------- helpers
__device__ __forceinline__ void gld_lds16(const void* gptr, void* lptr) {
    __builtin_amdgcn_global_load_lds(
        (const __attribute__((address_space(1))) unsigned int*)gptr,
        (__attribute__((address_space(3))) unsigned int*)lptr,
        16, 0, 0);
}

// ---------------------------------------------------------------- merged cast + zero
// blocks [0,6144): g -> g_bf ; [6144,6720): wq ; [6720,7296): wk ; [7296,9600): w_hn
__global__ void cast_all(const float* __restrict__ g, const float* __restrict__ wq,
                         const float* __restrict__ wk, const float* __restrict__ whn,
                         bf16* __restrict__ g_bf, bf16* __restrict__ Wcat) {
    int b = blockIdx.x;
    const float* src; bf16* dst; int off;
    if (b < 6144)      { src = g;   dst = g_bf;           off = 0;    }
    else if (b < 6720) { src = wq;  dst = Wcat;           off = 6144; }
    else if (b < 7296) { src = wk;  dst = Wcat + 589824;  off = 6720; }
    else               { src = whn; dst = Wcat + 1179648; off = 7296; }
    int i = ((b - off) * 256 + threadIdx.x) * 4;
    float4 v = *(const float4*)(src + i);
    bf16x4 o = { (bf16)v.x, (bf16)v.y, (bf16)v.z, (bf16)v.w };
    *(bf16x4*)(dst + i) = o;
}

__global__ void zero_ws(float* __restrict__ rowsum, float* __restrict__ out) {
    int i = blockIdx.x * 256 + threadIdx.x;
    rowsum[i] = 0.f;
    if (i == 0) out[0] = 0.f;
}

// ---------------------------------------------------------------- fused NT GEMM (32x32x16)
// C_full[M, 4608] = A[M,768] * Wcat[4608,768]^T  (bf16 in, fp32 acc)
// cols [0,768): q -> store QSCALE*acc as bf16 ; [768,1536): k -> store acc
// cols [1536,4608): Hopfield -> per-row sum of exp2(beta*log2e*acc) via atomicAdd
// BM=BN=128, BK=32, 256 threads (4 waves, 2x2 wave grid, 64x64 per wave, 2x2 32-tiles).
__global__ void gemm_fused(const bf16* __restrict__ A, const bf16* __restrict__ Bm,
                           bf16* __restrict__ qk, float* __restrict__ rowsum,
                           const float* __restrict__ beta_p, int Kd) {
    __shared__ __align__(16) bf16 As[128 * 32];
    __shared__ __align__(16) bf16 Bs[128 * 32];
    const int t = threadIdx.x;
    const int w = t >> 6, l = t & 63;
    const int wm = (w >> 1) * 64, wn = (w & 1) * 64;
    const int tile_m = blockIdx.x * 128;
    const int tile_n = blockIdx.y * 128;

    f32x16 acc[2][2];
#pragma unroll
    for (int i = 0; i < 2; i++)
#pragma unroll
        for (int j = 0; j < 2; j++)
#pragma unroll
            for (int q = 0; q < 16; q++) acc[i][j][q] = 0.f;

    const int row_a = t >> 2;     // 0..63
    const int seg   = t & 3;      // 16B segment within 64B row
    const int ar    = l & 31;     // row within a 32-tile
    const int ak    = (l >> 5) * 8;  // k-offset within a 16-step

    for (int k0 = 0; k0 < Kd; k0 += 32) {
#pragma unroll
        for (int i = 0; i < 2; i++) {
            int r = i * 64 + row_a;
            gld_lds16(A  + (size_t)(tile_m + r) * Kd + k0 + seg * 8, As + (i * 256 + t) * 8);
            gld_lds16(Bm + (size_t)(tile_n + r) * Kd + k0 + seg * 8, Bs + (i * 256 + t) * 8);
        }
        __builtin_amdgcn_s_waitcnt(0);
        __syncthreads();

        bf16x8 af[2][2], bfr[2][2];
#pragma unroll
        for (int mi = 0; mi < 2; mi++)
#pragma unroll
            for (int ks = 0; ks < 2; ks++) {
                af[mi][ks]  = *(const bf16x8*)(As + (wm + mi * 32 + ar) * 32 + ks * 16 + ak);
                bfr[mi][ks] = *(const bf16x8*)(Bs + (wn + mi * 32 + ar) * 32 + ks * 16 + ak);
            }
#pragma unroll
        for (int mi = 0; mi < 2; mi++)
#pragma unroll
            for (int nj = 0; nj < 2; nj++) {
                acc[mi][nj] = __builtin_amdgcn_mfma_f32_32x32x16_bf16(af[mi][0], bfr[nj][0], acc[mi][nj], 0, 0, 0);
                acc[mi][nj] = __builtin_amdgcn_mfma_f32_32x32x16_bf16(af[mi][1], bfr[nj][1], acc[mi][nj], 0, 0, 0);
            }
        __syncthreads();
    }

    // C/D layout (32x32, m74/m101-verified): col=lane&31, row=(reg&3)+8*(reg>>2)+4*(lane>>5)
    const int cc = l & 31;
    const int rh = 4 * (l >> 5);

    if (tile_n < 1536) {
        const float sc = (tile_n < 768) ? QSCALE : 1.0f;  // block-uniform (768 % 128 == 0)
#pragma unroll
        for (int mi = 0; mi < 2; mi++)
#pragma unroll
            for (int nj = 0; nj < 2; nj++)
#pragma unroll
                for (int reg = 0; reg < 16; reg++) {
                    int row = tile_m + wm + mi * 32 + (reg & 3) + 8 * (reg >> 2) + rh;
                    int col = tile_n + wn + nj * 32 + cc;
                    qk[(size_t)row * 1536 + col] = (bf16)(sc * acc[mi][nj][reg]);
                }
    } else {
        const float sc2 = beta_p[0] * LOG2E;
#pragma unroll
        for (int mi = 0; mi < 2; mi++)
#pragma unroll
            for (int reg = 0; reg < 16; reg++) {
                float s = __builtin_amdgcn_exp2f(sc2 * acc[mi][0][reg])
                        + __builtin_amdgcn_exp2f(sc2 * acc[mi][1][reg]);
                s += __shfl_xor(s, 1, 32);
                s += __shfl_xor(s, 2, 32);
                s += __shfl_xor(s, 4, 32);
                s += __shfl_xor(s, 8, 32);
                s += __shfl_xor(s, 16, 32);
                if ((l & 31) == 0)
                    atomicAdd(&rowsum[tile_m + wm + mi * 32 + (reg & 3) + 8 * (reg >> 2) + rh], s);
            }
    }
}

// ---------------------------------------------------------------- hopfield finalize
__global__ void hn_finalize(const float* __restrict__ rowsum, const float* __restrict__ beta_p,
                            float* __restrict__ out) {
    __shared__ float wpart[4];
    const int t = threadIdx.x, w = t >> 6, l = t & 63;
    float s = 0.f;
    for (int i = t; i < 8192; i += 256) s += __logf(rowsum[i]);
    for (int o = 32; o > 0; o >>= 1) s += __shfl_down(s, o, 64);
    if (l == 0) wpart[w] = s;
    __syncthreads();
    if (t == 0) atomicAdd(out, (-1.f / beta_p[0]) * (wpart[0] + wpart[1] + wpart[2] + wpart[3]));
}

// ---------------------------------------------------------------- fused attention lse
// QK: [8192, 1536] bf16; cols 0..767 = QSCALE*q(h*64+z), 768..1535 = k(h*64+z)
// grid (qt=8, h=12, b=8), block 256. Each block: 128 q-rows, full K=1024 loop.
// energy += -8 * sum_rows log( sum_k exp2(qs·k) )    (qs pre-scaled by 0.125*log2e)
__global__ void attn_energy(const bf16* __restrict__ QK, float* __restrict__ out) {
    __shared__ __align__(16) bf16 Qs[8 * 128 * 8];   // [zseg][qrow][8] 16KB
    __shared__ __align__(16) bf16 Ks[8 * 256 * 8];   // [zseg][krow][8] 32KB
    __shared__ float wpart[4];
    const int t = threadIdx.x, w = t >> 6, l = t & 63;
    const int qt = blockIdx.x, h = blockIdx.y, b = blockIdx.z;
    const size_t qbase = ((size_t)b * 1024 + qt * 128) * 1536 + h * 64;
    const size_t kcol  = 768 + h * 64;

    // stage Q tile (fragment-major: [zseg][row][8]) via async global->LDS
#pragma unroll
    for (int i = 0; i < 4; i++) {
        int c = i * 256 + t;          // 0..1023
        int row = c >> 3, zs = c & 7;
        gld_lds16(QK + qbase + (size_t)row * 1536 + zs * 8, Qs + (size_t)(i * 256 + t) * 8);
    }
    __builtin_amdgcn_s_waitcnt(0);
    __syncthreads();

    const int fr = l & 15, fg = l >> 4;
    bf16x8 af[2][2];
#pragma unroll
    for (int mi = 0; mi < 2; mi++)
#pragma unroll
        for (int ks = 0; ks < 2; ks++)
            af[mi][ks] = *(const bf16x8*)(Qs + (ks * 4 + fg) * 1024 + (w * 32 + mi * 16 + fr) * 8);

    float rs[2][4] = {};
    for (int kc = 0; kc < 4; kc++) {
        __syncthreads();   // protect Ks before restaging
#pragma unroll
        for (int i = 0; i < 8; i++) {
            int c = i * 256 + t;      // 0..2047
            int row = c >> 3, zs = c & 7;
            gld_lds16(QK + ((size_t)b * 1024 + kc * 256 + row) * 1536 + kcol + zs * 8,
                      Ks + (size_t)(i * 256 + t) * 8);
        }
        __builtin_amdgcn_s_waitcnt(0);
        __syncthreads();
#pragma unroll
        for (int nt = 0; nt < 16; nt++) {
            bf16x8 b0 = *(const bf16x8*)(Ks + (0 * 4 + fg) * 2048 + (nt * 16 + fr) * 8);
            bf16x8 b1 = *(const bf16x8*)(Ks + (1 * 4 + fg) * 2048 + (nt * 16 + fr) * 8);
#pragma unroll
            for (int mi = 0; mi < 2; mi++) {
                f32x4 acc;
#pragma unroll
                for (int q = 0; q < 4; q++) acc[q] = 0.f;
                acc = __builtin_amdgcn_mfma_f32_16x16x32_bf16(af[mi][0], b0, acc, 0, 0, 0);
                acc = __builtin_amdgcn_mfma_f32_16x16x32_bf16(af[mi][1], b1, acc, 0, 0, 0);
#pragma unroll
                for (int r = 0; r < 4; r++) rs[mi][r] += __builtin_amdgcn_exp2f(acc[r]);
            }
        }
    }

    float e = 0.f;
#pragma unroll
    for (int mi = 0; mi < 2; mi++)
#pragma unroll
        for (int r = 0; r < 4; r++) {
            float v = rs[mi][r];
            v += __shfl_xor(v, 1, 16);
            v += __shfl_xor(v, 2, 16);
            v += __shfl_xor(v, 4, 16);
            v += __shfl_xor(v, 8, 16);
            if ((l & 15) == 0) e += __logf(v);
        }
    e += __shfl_down(e, 32, 64);
    e += __shfl_down(e, 16, 64);
    if (l == 0) wpart[w] = e;
    __syncthreads();
    if (t == 0) atomicAdd(out, -8.f * (wpart[0] + wpart[1] + wpart[2] + wpart[3]));
}

// ---------------------------------------------------------------- launch
extern "C" void kernel_launch(void* const* d_in, const int* in_sizes, int n_in,
                              void* d_out, int out_size, void* d_ws, size_t ws_size,
                              hipStream_t stream) {
    const float* g    = (const float*)d_in[0];   // [8,1024,768]
    const float* wq   = (const float*)d_in[1];   // [12,64,768]
    const float* wk   = (const float*)d_in[2];   // [12,64,768]
    const float* w_hn = (const float*)d_in[3];   // [3072,768]
    const float* beta = (const float*)d_in[4];   // [1]
    float* out = (float*)d_out;

    char* ws = (char*)d_ws;
    bf16*  g_bf   = (bf16*)(ws);                          // 12,582,912 B
    bf16*  Wcat   = (bf16*)(ws + 12582912);               //  7,077,888 B (4608 x 768)
    bf16*  qk     = (bf16*)(ws + 19660800);               // 25,165,824 B
    float* rowsum = (float*)(ws + 44826624);              //     32,768 B (8192 f32)

    zero_ws<<<32, 256, 0, stream>>>(rowsum, out);
    cast_all<<<9600, 256, 0, stream>>>(g, wq, wk, w_hn, g_bf, Wcat);

    dim3 gg(64, 36);   // 8192/128 x 4608/128
    gemm_fused<<<gg, 256, 0, stream>>>(g_bf, Wcat, qk, rowsum, beta, 768);

    dim3 ga(8, 12, 8);
    attn_energy<<<ga, 256, 0, stream>>>(qk, out);
    hn_finalize<<<1, 256, 0, stream>>>(rowsum, beta, out);
}

// Round 4
// 193.898 us; speedup vs baseline: 1.1452x; 1.1452x over previous
//
#include <hip/hip_runtime.h>
#include <hip/hip_bf16.h>
#include <stdint.h>
#include <stddef.h>

typedef __bf16 bf16;
typedef __bf16 bf16x4 __attribute__((ext_vector_type(4)));
typedef __bf16 bf16x8 __attribute__((ext_vector_type(8)));
typedef float  f32x4  __attribute__((ext_vector_type(4)));

#define LOG2E 1.44269504f
#define QSCALE 0.18033688f   /* 0.125 * log2(e) */

// ---------------------------------------------------------------- helpers
__device__ __forceinline__ void gld_lds16(const void* gptr, void* lptr) {
    __builtin_amdgcn_global_load_lds(
        (const __attribute__((address_space(1))) unsigned int*)gptr,
        (__attribute__((address_space(3))) unsigned int*)lptr,
        16, 0, 0);
}

// ---------------------------------------------------------------- merged cast
// blocks [0,6144): g -> g_bf ; [6144,6720): wq ; [6720,7296): wk ; [7296,9600): w_hn
__global__ void cast_all(const float* __restrict__ g, const float* __restrict__ wq,
                         const float* __restrict__ wk, const float* __restrict__ whn,
                         bf16* __restrict__ g_bf, bf16* __restrict__ Wcat) {
    int b = blockIdx.x;
    const float* src; bf16* dst; int off;
    if (b < 6144)      { src = g;   dst = g_bf;           off = 0;    }
    else if (b < 6720) { src = wq;  dst = Wcat;           off = 6144; }
    else if (b < 7296) { src = wk;  dst = Wcat + 589824;  off = 6720; }
    else               { src = whn; dst = Wcat + 1179648; off = 7296; }
    int i = ((b - off) * 256 + threadIdx.x) * 4;
    float4 v = *(const float4*)(src + i);
    bf16x4 o = { (bf16)v.x, (bf16)v.y, (bf16)v.z, (bf16)v.w };
    *(bf16x4*)(dst + i) = o;
}

__global__ void zero_ws(float* __restrict__ rowsum, float* __restrict__ out) {
    int i = blockIdx.x * 256 + threadIdx.x;
    rowsum[i] = 0.f;
    if (i == 0) out[0] = 0.f;
}

// ---------------------------------------------------------------- fused NT GEMM
// C_full[M, 4608] = A[M,768] * Wcat[4608,768]^T  (bf16 in, fp32 acc), 16x16x32 MFMA
// cols [0,768): q -> store QSCALE*acc ; [768,1536): k -> store acc
// cols [1536,4608): Hopfield -> per-row sum exp2(beta*log2e*acc) via atomicAdd
// BM=BN=128, BK=64, 256 threads (2x2 waves, 64x64 each).
// LDS: As[row][seg] (seg = 16B unit) holds GLOBAL segment (seg ^ (row&7)) —
// XOR swizzle makes fragment reads hit all 8 bank-quads (2-way max = free).
__global__ void gemm_fused(const bf16* __restrict__ A, const bf16* __restrict__ Bm,
                           bf16* __restrict__ qk, float* __restrict__ rowsum,
                           const float* __restrict__ beta_p) {
    __shared__ __align__(16) bf16 As[128 * 64];
    __shared__ __align__(16) bf16 Bs[128 * 64];
    const int t = threadIdx.x;
    const int w = t >> 6, l = t & 63;
    const int wm = (w >> 1) * 64, wn = (w & 1) * 64;
    const int tile_m = blockIdx.x * 128;
    const int tile_n = blockIdx.y * 128;

    f32x4 acc[4][4];
#pragma unroll
    for (int i = 0; i < 4; i++)
#pragma unroll
        for (int j = 0; j < 4; j++)
#pragma unroll
            for (int q = 0; q < 4; q++) acc[i][j][q] = 0.f;

    // staging: slot s = i*256+t -> row = i*32 + (t>>3), seg = t&7; fetch global
    // segment (seg ^ (row&7)).  (i*32 doesn't change row&7, so swz is i-invariant.)
    const int srow = t >> 3;               // 0..31
    const int sswz = (t & 7) ^ (srow & 7); // swizzled global segment
    const bf16* gA = A  + (size_t)(tile_m + srow) * 768 + sswz * 8;
    const bf16* gB = Bm + (size_t)(tile_n + srow) * 768 + sswz * 8;

    const int fr = l & 15, fg = l >> 4;

    for (int k0 = 0; k0 < 768; k0 += 64) {
#pragma unroll
        for (int i = 0; i < 4; i++) {
            gld_lds16(gA + (size_t)i * 32 * 768 + k0, As + (i * 256 + t) * 8);
            gld_lds16(gB + (size_t)i * 32 * 768 + k0, Bs + (i * 256 + t) * 8);
        }
        __builtin_amdgcn_s_waitcnt(0);
        __syncthreads();

#pragma unroll
        for (int ks = 0; ks < 2; ks++) {
            const int swz = (((ks * 4 + fg) ^ (fr & 7))) * 8;  // row&7 == fr&7
            bf16x8 af[4], bfr[4];
#pragma unroll
            for (int i = 0; i < 4; i++) {
                af[i]  = *(const bf16x8*)(As + (wm + i * 16 + fr) * 64 + swz);
                bfr[i] = *(const bf16x8*)(Bs + (wn + i * 16 + fr) * 64 + swz);
            }
#pragma unroll
            for (int i = 0; i < 4; i++)
#pragma unroll
                for (int j = 0; j < 4; j++)
                    acc[i][j] = __builtin_amdgcn_mfma_f32_16x16x32_bf16(af[i], bfr[j], acc[i][j], 0, 0, 0);
        }
        __syncthreads();
    }

    // C/D layout: col=lane&15, row=(lane>>4)*4+reg  [m89-verified]
    const int cr = fg * 4, cc = fr;

    if (tile_n < 1536) {
        const float sc = (tile_n < 768) ? QSCALE : 1.0f;  // block-uniform (768%128==0)
#pragma unroll
        for (int i = 0; i < 4; i++)
#pragma unroll
            for (int j = 0; j < 4; j++)
#pragma unroll
                for (int r = 0; r < 4; r++) {
                    int row = tile_m + wm + i * 16 + cr + r;
                    int col = tile_n + wn + j * 16 + cc;
                    qk[(size_t)row * 1536 + col] = (bf16)(sc * acc[i][j][r]);
                }
    } else {
        const float sc2 = beta_p[0] * LOG2E;
#pragma unroll
        for (int i = 0; i < 4; i++)
#pragma unroll
            for (int r = 0; r < 4; r++) {
                float s = 0.f;
#pragma unroll
                for (int j = 0; j < 4; j++) s += __builtin_amdgcn_exp2f(sc2 * acc[i][j][r]);
                s += __shfl_xor(s, 1, 16);
                s += __shfl_xor(s, 2, 16);
                s += __shfl_xor(s, 4, 16);
                s += __shfl_xor(s, 8, 16);
                if ((l & 15) == 0)
                    atomicAdd(&rowsum[tile_m + wm + i * 16 + cr + r], s);
            }
    }
}

// ---------------------------------------------------------------- hopfield finalize
__global__ void hn_finalize(const float* __restrict__ rowsum, const float* __restrict__ beta_p,
                            float* __restrict__ out) {
    __shared__ float wpart[4];
    const int t = threadIdx.x, w = t >> 6, l = t & 63;
    float s = 0.f;
    for (int i = t; i < 8192; i += 256) s += __logf(rowsum[i]);
    for (int o = 32; o > 0; o >>= 1) s += __shfl_down(s, o, 64);
    if (l == 0) wpart[w] = s;
    __syncthreads();
    if (t == 0) atomicAdd(out, (-1.f / beta_p[0]) * (wpart[0] + wpart[1] + wpart[2] + wpart[3]));
}

// ---------------------------------------------------------------- fused attention lse
// QK: [8192, 1536] bf16; cols 0..767 = QSCALE*q(h*64+z), 768..1535 = k(h*64+z)
// grid (qt=8, h=12, b=8), block 256. energy += -8 * sum_rows log(sum_k exp2(qs·k))
__global__ void attn_energy(const bf16* __restrict__ QK, float* __restrict__ out) {
    __shared__ __align__(16) bf16 Qs[8 * 128 * 8];   // [zseg][qrow][8] 16KB
    __shared__ __align__(16) bf16 Ks[8 * 256 * 8];   // [zseg][krow][8] 32KB
    __shared__ float wpart[4];
    const int t = threadIdx.x, w = t >> 6, l = t & 63;
    const int qt = blockIdx.x, h = blockIdx.y, b = blockIdx.z;
    const size_t qbase = ((size_t)b * 1024 + qt * 128) * 1536 + h * 64;
    const size_t kcol  = 768 + h * 64;

#pragma unroll
    for (int i = 0; i < 4; i++) {
        int c = i * 256 + t;          // 0..1023
        int row = c >> 3, zs = c & 7;
        gld_lds16(QK + qbase + (size_t)row * 1536 + zs * 8, Qs + (size_t)(i * 256 + t) * 8);
    }
    __builtin_amdgcn_s_waitcnt(0);
    __syncthreads();

    const int fr = l & 15, fg = l >> 4;
    bf16x8 af[2][2];
#pragma unroll
    for (int mi = 0; mi < 2; mi++)
#pragma unroll
        for (int ks = 0; ks < 2; ks++)
            af[mi][ks] = *(const bf16x8*)(Qs + (ks * 4 + fg) * 1024 + (w * 32 + mi * 16 + fr) * 8);

    float rs[2][4] = {};
    for (int kc = 0; kc < 4; kc++) {
        __syncthreads();
#pragma unroll
        for (int i = 0; i < 8; i++) {
            int c = i * 256 + t;      // 0..2047
            int row = c >> 3, zs = c & 7;
            gld_lds16(QK + ((size_t)b * 1024 + kc * 256 + row) * 1536 + kcol + zs * 8,
                      Ks + (size_t)(i * 256 + t) * 8);
        }
        __builtin_amdgcn_s_waitcnt(0);
        __syncthreads();
#pragma unroll
        for (int nt = 0; nt < 16; nt++) {
            bf16x8 b0 = *(const bf16x8*)(Ks + (0 * 4 + fg) * 2048 + (nt * 16 + fr) * 8);
            bf16x8 b1 = *(const bf16x8*)(Ks + (1 * 4 + fg) * 2048 + (nt * 16 + fr) * 8);
#pragma unroll
            for (int mi = 0; mi < 2; mi++) {
                f32x4 acc;
#pragma unroll
                for (int q = 0; q < 4; q++) acc[q] = 0.f;
                acc = __builtin_amdgcn_mfma_f32_16x16x32_bf16(af[mi][0], b0, acc, 0, 0, 0);
                acc = __builtin_amdgcn_mfma_f32_16x16x32_bf16(af[mi][1], b1, acc, 0, 0, 0);
#pragma unroll
                for (int r = 0; r < 4; r++) rs[mi][r] += __builtin_amdgcn_exp2f(acc[r]);
            }
        }
    }

    float e = 0.f;
#pragma unroll
    for (int mi = 0; mi < 2; mi++)
#pragma unroll
        for (int r = 0; r < 4; r++) {
            float v = rs[mi][r];
            v += __shfl_xor(v, 1, 16);
            v += __shfl_xor(v, 2, 16);
            v += __shfl_xor(v, 4, 16);
            v += __shfl_xor(v, 8, 16);
            if ((l & 15) == 0) e += __logf(v);
        }
    e += __shfl_down(e, 32, 64);
    e += __shfl_down(e, 16, 64);
    if (l == 0) wpart[w] = e;
    __syncthreads();
    if (t == 0) atomicAdd(out, -8.f * (wpart[0] + wpart[1] + wpart[2] + wpart[3]));
}

// ---------------------------------------------------------------- launch
extern "C" void kernel_launch(void* const* d_in, const int* in_sizes, int n_in,
                              void* d_out, int out_size, void* d_ws, size_t ws_size,
                              hipStream_t stream) {
    const float* g    = (const float*)d_in[0];   // [8,1024,768]
    const float* wq   = (const float*)d_in[1];   // [12,64,768]
    const float* wk   = (const float*)d_in[2];   // [12,64,768]
    const float* w_hn = (const float*)d_in[3];   // [3072,768]
    const float* beta = (const float*)d_in[4];   // [1]
    float* out = (float*)d_out;

    char* ws = (char*)d_ws;
    bf16*  g_bf   = (bf16*)(ws);                          // 12,582,912 B
    bf16*  Wcat   = (bf16*)(ws + 12582912);               //  7,077,888 B (4608 x 768)
    bf16*  qk     = (bf16*)(ws + 19660800);               // 25,165,824 B
    float* rowsum = (float*)(ws + 44826624);              //     32,768 B (8192 f32)

    zero_ws<<<32, 256, 0, stream>>>(rowsum, out);
    cast_all<<<9600, 256, 0, stream>>>(g, wq, wk, w_hn, g_bf, Wcat);

    dim3 gg(64, 36);   // 8192/128 x 4608/128
    gemm_fused<<<gg, 256, 0, stream>>>(g_bf, Wcat, qk, rowsum, beta);

    dim3 ga(8, 12, 8);
    attn_energy<<<ga, 256, 0, stream>>>(qk, out);
    hn_finalize<<<1, 256, 0, stream>>>(rowsum, beta, out);
}